// Round 3
// baseline (151.013 us; speedup 1.0000x reference)
//
#include <hip/hip_runtime.h>

// src:  [1,2,160,192,224] f32
// flow: [1,3,160,192,224] f32  (channel i displaces spatial dim i: z,y,x)
// out:  [1,2,160,192,224] f32
constexpr int D = 160;
constexpr int H = 192;
constexpr int W = 224;
constexpr int N = D * H * W;

// Block tile: 4 (z) x 16 (y) x 16 (x) voxels = 1024 voxels, 512 threads (2 vox/thread).
// Halo: flow ~ N(0,1) so |disp| < 6 w.h.p.; corners need [v-6, v+6] -> tile extent +12.
constexpr int TZ  = 16;   // 4 + 12
constexpr int TY  = 28;   // 16 + 12
constexpr int TXS = 32;   // staged x extent (16 + 12 = 28, padded to 32 for the loop)
constexpr int XSTRIDE = 33;  // padded x stride (in channel-pairs) -> spreads LDS banks

typedef float f2v __attribute__((ext_vector_type(2)));

__device__ __forceinline__ f2v ld2_lds(const float* p) {
    f2v v;
    __builtin_memcpy(&v, p, sizeof(v));   // ds_read_b64 (8B-aligned: even dword index)
    return v;
}

__global__ __launch_bounds__(512, 1) void warp3d_lds_kernel(
    const float* __restrict__ src,
    const float* __restrict__ flow,
    float* __restrict__ out)
{
    // interleaved tile: dword index = ((s*TY + t)*XSTRIDE + u)*2 + ch
    __shared__ float tile[TZ * TY * XSTRIDE * 2];  // 29,568 floats = 115.5 KB

    const int tid = threadIdx.x;
    const int bx = blockIdx.x, by = blockIdx.y, bz = blockIdx.z;
    const int tz0 = bz * 4  - 6;
    const int ty0 = by * 16 - 6;
    const int tx0 = bx * 16 - 6;

    // ---- gather-phase thread mapping (2 voxels per thread, z and z+1) ----
    const int lx  = tid & 15;
    const int ly  = (tid >> 4) & 15;
    const int lzh = tid >> 8;              // 0..1
    const int x   = bx * 16 + lx;
    const int y   = by * 16 + ly;
    const int zv  = bz * 4 + lzh * 2;      // voxel z for k=0; k=1 adds 1

    const int vidx0 = (zv * H + y) * W + x;
    const int vidx1 = vidx0 + H * W;

    // prefetch flow early so HBM latency hides under staging
    const float flz0 = flow[vidx0], fly0 = flow[N + vidx0], flx0 = flow[2 * N + vidx0];
    const float flz1 = flow[vidx1], fly1 = flow[N + vidx1], flx1 = flow[2 * N + vidx1];

    // ---- stage: worker s = tid>>5 owns one z-slab, lane u = tid&31 owns one x ----
    {
        const int u = tid & 31;
        const int s = tid >> 5;            // [0,16)
        const int gz = min(max(tz0 + s, 0), D - 1);
        const int gx = min(max(tx0 + u, 0), W - 1);
        const int zrow = gz * H;
        int ld = (s * TY * XSTRIDE + u) * 2;
        #pragma unroll 4
        for (int t = 0; t < TY; ++t) {
            const int gy = min(max(ty0 + t, 0), H - 1);
            const int ga = (zrow + gy) * W + gx;
            tile[ld]     = src[ga];        // ch0
            tile[ld + 1] = src[N + ga];    // ch1
            ld += XSTRIDE * 2;
        }
    }
    __syncthreads();

    // ---- gather: 2 voxels per thread ----
    #pragma unroll
    for (int k = 0; k < 2; ++k) {
        const int zz = zv + k;
        const float flz = k ? flz1 : flz0;
        const float fly = k ? fly1 : fly0;
        const float flx = k ? flx1 : flx0;

        const float pz = flz + (float)zz;
        const float py = fly + (float)y;
        const float px = flx + (float)x;

        const float z0f = floorf(pz), y0f = floorf(py), x0f = floorf(px);
        const float fz = pz - z0f, fy = py - y0f, fx = px - x0f;
        const int z0 = (int)z0f, y0 = (int)y0f, x0 = (int)x0f;

        // zeros padding folded into per-axis weights (validity on GLOBAL coords)
        const float wz0 = ((unsigned)z0       < (unsigned)D) ? (1.0f - fz) : 0.0f;
        const float wz1 = ((unsigned)(z0 + 1) < (unsigned)D) ? fz          : 0.0f;
        const float wy0 = ((unsigned)y0       < (unsigned)H) ? (1.0f - fy) : 0.0f;
        const float wy1 = ((unsigned)(y0 + 1) < (unsigned)H) ? fy          : 0.0f;
        const float wx0 = ((unsigned)x0       < (unsigned)W) ? (1.0f - fx) : 0.0f;
        const float wx1 = ((unsigned)(x0 + 1) < (unsigned)W) ? fx          : 0.0f;

        const float w00 = wz0 * wy0, w01 = wz0 * wy1;
        const float w10 = wz1 * wy0, w11 = wz1 * wy1;

        float acc0, acc1;

        // tile-local corner coords (unclamped; staging already clamped at edges,
        // so in-tile reads reproduce volume-edge clamp semantics exactly)
        const int a0 = z0 - tz0;
        const int b0 = y0 - ty0;
        const int u0 = x0 - tx0;
        const bool intile = ((unsigned)a0 < (unsigned)(TZ - 1)) &&
                            ((unsigned)b0 < (unsigned)(TY - 1)) &&
                            ((unsigned)u0 < (unsigned)(TXS - 1));

        if (intile) {
            const int r00 = ((a0 * TY + b0) * XSTRIDE + u0) * 2;
            const int r01 = r00 + XSTRIDE * 2;       // b0+1
            const int r10 = r00 + TY * XSTRIDE * 2;  // a0+1
            const int r11 = r10 + XSTRIDE * 2;

            const f2v q00a = ld2_lds(&tile[r00]),     q00b = ld2_lds(&tile[r00 + 2]);
            const f2v q01a = ld2_lds(&tile[r01]),     q01b = ld2_lds(&tile[r01 + 2]);
            const f2v q10a = ld2_lds(&tile[r10]),     q10b = ld2_lds(&tile[r10 + 2]);
            const f2v q11a = ld2_lds(&tile[r11]),     q11b = ld2_lds(&tile[r11 + 2]);

            acc0 = w00 * (wx0 * q00a[0] + wx1 * q00b[0])
                 + w01 * (wx0 * q01a[0] + wx1 * q01b[0])
                 + w10 * (wx0 * q10a[0] + wx1 * q10b[0])
                 + w11 * (wx0 * q11a[0] + wx1 * q11b[0]);
            acc1 = w00 * (wx0 * q00a[1] + wx1 * q00b[1])
                 + w01 * (wx0 * q01a[1] + wx1 * q01b[1])
                 + w10 * (wx0 * q10a[1] + wx1 * q10b[1])
                 + w11 * (wx0 * q11a[1] + wx1 * q11b[1]);
        } else {
            // |flow| >= 6 (prob ~1e-8/voxel): exact global-memory fallback
            const int zc0 = min(max(z0, 0), D - 1), zc1 = min(max(z0 + 1, 0), D - 1);
            const int yc0 = min(max(y0, 0), H - 1), yc1 = min(max(y0 + 1, 0), H - 1);
            const int xc0 = min(max(x0, 0), W - 1), xc1 = min(max(x0 + 1, 0), W - 1);
            const int g00 = (zc0 * H + yc0) * W, g01 = (zc0 * H + yc1) * W;
            const int g10 = (zc1 * H + yc0) * W, g11 = (zc1 * H + yc1) * W;
            acc0 = w00 * (wx0 * src[g00 + xc0] + wx1 * src[g00 + xc1])
                 + w01 * (wx0 * src[g01 + xc0] + wx1 * src[g01 + xc1])
                 + w10 * (wx0 * src[g10 + xc0] + wx1 * src[g10 + xc1])
                 + w11 * (wx0 * src[g11 + xc0] + wx1 * src[g11 + xc1]);
            acc1 = w00 * (wx0 * src[N + g00 + xc0] + wx1 * src[N + g00 + xc1])
                 + w01 * (wx0 * src[N + g01 + xc0] + wx1 * src[N + g01 + xc1])
                 + w10 * (wx0 * src[N + g10 + xc0] + wx1 * src[N + g10 + xc1])
                 + w11 * (wx0 * src[N + g11 + xc0] + wx1 * src[N + g11 + xc1]);
        }

        const int vidx = k ? vidx1 : vidx0;
        out[vidx]     = acc0;
        out[N + vidx] = acc1;
    }
}

extern "C" void kernel_launch(void* const* d_in, const int* in_sizes, int n_in,
                              void* d_out, int out_size, void* d_ws, size_t ws_size,
                              hipStream_t stream) {
    const float* src  = (const float*)d_in[0];
    const float* flow = (const float*)d_in[1];
    float* out = (float*)d_out;

    dim3 grid(W / 16, H / 16, D / 4);   // 14 x 12 x 40 = 6720 blocks
    warp3d_lds_kernel<<<grid, 512, 0, stream>>>(src, flow, out);
}

// Round 4
// 80.515 us; speedup vs baseline: 1.8756x; 1.8756x over previous
//
#include <hip/hip_runtime.h>
#include <hip/hip_fp16.h>

// src:  [1,2,160,192,224] f32, flow: [1,3,160,192,224] f32, out: [1,2,160,192,224] f32
constexpr int D = 160;
constexpr int H = 192;
constexpr int W = 224;
constexpr int N = D * H * W;

// Output tile per block: 8(z) x 16(y) x 56(x) = 7168 voxels, 1024 threads, 7 vox/thread.
// Halo 4 each side (|flow|>=4 near a tile face -> exact global fallback, P ~ 1e-5).
constexpr int BZ = 8, BY = 16, BX = 56;
constexpr int HA = 4;
constexpr int SZ = BZ + 2 * HA;   // 16
constexpr int SY = BY + 2 * HA;   // 24
constexpr int SX = 64;            // BX + 8, wave-aligned staging rows
constexpr int NTHR = 1024;
constexpr int VPT  = (BZ * BY * BX) / NTHR;  // 7

struct h2p { __half2 a, b; };  // (ch0,ch1)@x0 , (ch0,ch1)@x1

__device__ __forceinline__ h2p ld_pair(const __half2* p) {
    h2p v;
    __builtin_memcpy(&v, p, sizeof(v));   // 8B @ 4B align -> ds_read2_b32
    return v;
}

__global__ __launch_bounds__(NTHR, 1) void warp3d_h2_kernel(
    const float* __restrict__ src,
    const float* __restrict__ flow,
    float* __restrict__ out)
{
    __shared__ __half2 tile[SZ * SY * SX];   // 24576 * 4B = 96 KB

    const int tid = threadIdx.x;
    const int bx = blockIdx.x, by = blockIdx.y, bz = blockIdx.z;
    const int tz0 = bz * BZ - HA;
    const int ty0 = by * BY - HA;
    const int tx0 = bx * BX - HA;

    // ---- hoist flow loads (HBM latency hides under staging) ----
    int   vidx[VPT];
    float pz[VPT], py[VPT], px[VPT];
    #pragma unroll
    for (int i = 0; i < VPT; ++i) {
        const int v  = tid + i * NTHR;
        const int lx = v % BX;
        const int q  = v / BX;
        const int ly = q % BY;
        const int lz = q / BY;
        const int gx = bx * BX + lx;
        const int gy = by * BY + ly;
        const int gz = bz * BZ + lz;
        vidx[i] = (gz * H + gy) * W + gx;
        pz[i] = flow[vidx[i]]         + (float)gz;
        py[i] = flow[N + vidx[i]]     + (float)gy;
        px[i] = flow[2 * N + vidx[i]] + (float)gx;
    }

    // ---- stage: 384 rows of 64; wave-row = tid>>6, lane = tid&63 ----
    {
        const int u    = tid & 63;
        const int wrow = tid >> 6;            // 0..15
        const int gx   = min(max(tx0 + u, 0), W - 1);
        for (int r = wrow; r < SZ * SY; r += 16) {
            const int s  = r / SY;
            const int t  = r - s * SY;
            const int gz = min(max(tz0 + s, 0), D - 1);
            const int gy = min(max(ty0 + t, 0), H - 1);
            const int ga = (gz * H + gy) * W + gx;
            tile[r * SX + u] = __floats2half2_rn(src[ga], src[N + ga]);
        }
    }
    __syncthreads();

    // ---- gather: 7 voxels/thread ----
    #pragma unroll
    for (int i = 0; i < VPT; ++i) {
        const float z0f = floorf(pz[i]), y0f = floorf(py[i]), x0f = floorf(px[i]);
        const float fz = pz[i] - z0f, fy = py[i] - y0f, fx = px[i] - x0f;
        const int z0 = (int)z0f, y0 = (int)y0f, x0 = (int)x0f;

        // zeros padding folded into per-axis weights (validity on GLOBAL coords)
        const float wz0 = ((unsigned)z0       < (unsigned)D) ? (1.0f - fz) : 0.0f;
        const float wz1 = ((unsigned)(z0 + 1) < (unsigned)D) ? fz          : 0.0f;
        const float wy0 = ((unsigned)y0       < (unsigned)H) ? (1.0f - fy) : 0.0f;
        const float wy1 = ((unsigned)(y0 + 1) < (unsigned)H) ? fy          : 0.0f;
        const float wx0 = ((unsigned)x0       < (unsigned)W) ? (1.0f - fx) : 0.0f;
        const float wx1 = ((unsigned)(x0 + 1) < (unsigned)W) ? fx          : 0.0f;

        const float w00 = wz0 * wy0, w01 = wz0 * wy1;
        const float w10 = wz1 * wy0, w11 = wz1 * wy1;

        // tile-local corner coords (staging clamped at volume edges, so in-tile
        // reads reproduce clamp semantics; weight-0 corners are harmless)
        const int a0 = z0 - tz0;
        const int b0 = y0 - ty0;
        const int u0 = x0 - tx0;
        const bool intile = ((unsigned)a0 < (unsigned)(SZ - 1)) &&
                            ((unsigned)b0 < (unsigned)(SY - 1)) &&
                            ((unsigned)u0 < (unsigned)(SX - 1));

        float acc0, acc1;
        if (intile) {
            const int r00 = (a0 * SY + b0) * SX + u0;
            const h2p q00 = ld_pair(&tile[r00]);
            const h2p q01 = ld_pair(&tile[r00 + SX]);
            const h2p q10 = ld_pair(&tile[r00 + SY * SX]);
            const h2p q11 = ld_pair(&tile[r00 + SY * SX + SX]);

            const float2 f00a = __half22float2(q00.a), f00b = __half22float2(q00.b);
            const float2 f01a = __half22float2(q01.a), f01b = __half22float2(q01.b);
            const float2 f10a = __half22float2(q10.a), f10b = __half22float2(q10.b);
            const float2 f11a = __half22float2(q11.a), f11b = __half22float2(q11.b);

            acc0 = w00 * (wx0 * f00a.x + wx1 * f00b.x)
                 + w01 * (wx0 * f01a.x + wx1 * f01b.x)
                 + w10 * (wx0 * f10a.x + wx1 * f10b.x)
                 + w11 * (wx0 * f11a.x + wx1 * f11b.x);
            acc1 = w00 * (wx0 * f00a.y + wx1 * f00b.y)
                 + w01 * (wx0 * f01a.y + wx1 * f01b.y)
                 + w10 * (wx0 * f10a.y + wx1 * f10b.y)
                 + w11 * (wx0 * f11a.y + wx1 * f11b.y);
        } else {
            // rare exact fallback: planar fp32 global reads, clamped, weight-zeroed
            const int zc0 = min(max(z0, 0), D - 1), zc1 = min(max(z0 + 1, 0), D - 1);
            const int yc0 = min(max(y0, 0), H - 1), yc1 = min(max(y0 + 1, 0), H - 1);
            const int xc0 = min(max(x0, 0), W - 1), xc1 = min(max(x0 + 1, 0), W - 1);
            const int g00 = (zc0 * H + yc0) * W, g01 = (zc0 * H + yc1) * W;
            const int g10 = (zc1 * H + yc0) * W, g11 = (zc1 * H + yc1) * W;
            acc0 = w00 * (wx0 * src[g00 + xc0] + wx1 * src[g00 + xc1])
                 + w01 * (wx0 * src[g01 + xc0] + wx1 * src[g01 + xc1])
                 + w10 * (wx0 * src[g10 + xc0] + wx1 * src[g10 + xc1])
                 + w11 * (wx0 * src[g11 + xc0] + wx1 * src[g11 + xc1]);
            acc1 = w00 * (wx0 * src[N + g00 + xc0] + wx1 * src[N + g00 + xc1])
                 + w01 * (wx0 * src[N + g01 + xc0] + wx1 * src[N + g01 + xc1])
                 + w10 * (wx0 * src[N + g10 + xc0] + wx1 * src[N + g10 + xc1])
                 + w11 * (wx0 * src[N + g11 + xc0] + wx1 * src[N + g11 + xc1]);
        }

        out[vidx[i]]     = acc0;
        out[N + vidx[i]] = acc1;
    }
}

extern "C" void kernel_launch(void* const* d_in, const int* in_sizes, int n_in,
                              void* d_out, int out_size, void* d_ws, size_t ws_size,
                              hipStream_t stream) {
    const float* src  = (const float*)d_in[0];
    const float* flow = (const float*)d_in[1];
    float* out = (float*)d_out;

    dim3 grid(W / BX, H / BY, D / BZ);   // 4 x 12 x 20 = 960 blocks
    warp3d_h2_kernel<<<grid, NTHR, 0, stream>>>(src, flow, out);
}

// Round 5
// 79.909 us; speedup vs baseline: 1.8898x; 1.0076x over previous
//
#include <hip/hip_runtime.h>
#include <hip/hip_fp16.h>

// src:  [1,2,160,192,224] f32, flow: [1,3,160,192,224] f32, out: [1,2,160,192,224] f32
constexpr int D = 160;
constexpr int H = 192;
constexpr int W = 224;
constexpr int N = D * H * W;

// Output tile: 8(z) x 8(y) x 56(x) = 3584 voxels. 896 threads (14 waves), 4 vox/thread.
// Staged (halo 4): 16 x 16 x 64 half2 = 64 KB exactly -> 2 blocks/CU (128 KB of 160 KB),
// 28 waves/CU resident: block A's gather overlaps block B's staging.
constexpr int BZ = 8, BY = 8, BX = 56;
constexpr int HA = 4;
constexpr int SZ = 16;   // BZ + 8
constexpr int SY = 16;   // BY + 8  (power of 2 -> shift addressing)
constexpr int SX = 64;   // BX + 8  (power of 2, wave-aligned staging rows)
constexpr int NTHR = 896;
constexpr int VPT  = (BZ * BY * BX) / NTHR;  // 4

struct h2p { __half2 a, b; };  // (ch0,ch1)@x0 , (ch0,ch1)@x1

__device__ __forceinline__ h2p ld_pair(const __half2* p) {
    h2p v;
    __builtin_memcpy(&v, p, sizeof(v));   // 8B @ 4B align
    return v;
}

__global__ __launch_bounds__(NTHR, 1) void warp3d_h2_kernel(
    const float* __restrict__ src,
    const float* __restrict__ flow,
    float* __restrict__ out)
{
    __shared__ __half2 tile[SZ * SY * SX];   // 16384 * 4B = 64 KB

    const int tid = threadIdx.x;
    const int bx = blockIdx.x, by = blockIdx.y, bz = blockIdx.z;
    const int tz0 = bz * BZ - HA;
    const int ty0 = by * BY - HA;
    const int tx0 = bx * BX - HA;

    // ---- hoist flow loads (HBM latency hides under staging) ----
    int   vidx[VPT];
    float pz[VPT], py[VPT], px[VPT];
    #pragma unroll
    for (int i = 0; i < VPT; ++i) {
        const int v  = tid + i * NTHR;
        const int lx = v % BX;
        const int q  = v / BX;
        const int ly = q % BY;
        const int lz = q / BY;
        const int gx = bx * BX + lx;
        const int gy = by * BY + ly;
        const int gz = bz * BZ + lz;
        vidx[i] = (gz * H + gy) * W + gx;
        pz[i] = flow[vidx[i]]         + (float)gz;
        py[i] = flow[N + vidx[i]]     + (float)gy;
        px[i] = flow[2 * N + vidx[i]] + (float)gx;
    }

    // ---- stage: 256 rows of 64 lanes; wave-row = tid>>6 (0..13), stride 14 ----
    {
        const int u    = tid & 63;
        const int wrow = tid >> 6;
        const int gx   = min(max(tx0 + u, 0), W - 1);
        for (int r = wrow; r < SZ * SY; r += NTHR / 64) {
            const int s  = r >> 4;
            const int t  = r & 15;
            const int gz = min(max(tz0 + s, 0), D - 1);
            const int gy = min(max(ty0 + t, 0), H - 1);
            const int ga = (gz * H + gy) * W + gx;
            tile[(r << 6) + u] = __floats2half2_rn(src[ga], src[N + ga]);
        }
    }
    __syncthreads();

    // ---- gather: 4 voxels/thread ----
    #pragma unroll
    for (int i = 0; i < VPT; ++i) {
        const float z0f = floorf(pz[i]), y0f = floorf(py[i]), x0f = floorf(px[i]);
        const float fz = pz[i] - z0f, fy = py[i] - y0f, fx = px[i] - x0f;
        const int z0 = (int)z0f, y0 = (int)y0f, x0 = (int)x0f;

        // zeros padding folded into per-axis weights (validity on GLOBAL coords)
        const float wz0 = ((unsigned)z0       < (unsigned)D) ? (1.0f - fz) : 0.0f;
        const float wz1 = ((unsigned)(z0 + 1) < (unsigned)D) ? fz          : 0.0f;
        const float wy0 = ((unsigned)y0       < (unsigned)H) ? (1.0f - fy) : 0.0f;
        const float wy1 = ((unsigned)(y0 + 1) < (unsigned)H) ? fy          : 0.0f;
        const float wx0 = ((unsigned)x0       < (unsigned)W) ? (1.0f - fx) : 0.0f;
        const float wx1 = ((unsigned)(x0 + 1) < (unsigned)W) ? fx          : 0.0f;

        const float w00 = wz0 * wy0, w01 = wz0 * wy1;
        const float w10 = wz1 * wy0, w11 = wz1 * wy1;

        // tile-local corner coords (staging clamped at volume edges, so in-tile
        // reads reproduce clamp semantics; weight-0 corners are harmless)
        const int a0 = z0 - tz0;
        const int b0 = y0 - ty0;
        const int u0 = x0 - tx0;
        const bool intile = ((unsigned)a0 < (unsigned)(SZ - 1)) &&
                            ((unsigned)b0 < (unsigned)(SY - 1)) &&
                            ((unsigned)u0 < (unsigned)(SX - 1));

        float acc0, acc1;
        if (intile) {
            const int r00 = ((a0 << 4) + b0 << 6) + u0;
            const h2p q00 = ld_pair(&tile[r00]);
            const h2p q01 = ld_pair(&tile[r00 + SX]);
            const h2p q10 = ld_pair(&tile[r00 + SY * SX]);
            const h2p q11 = ld_pair(&tile[r00 + SY * SX + SX]);

            const float2 f00a = __half22float2(q00.a), f00b = __half22float2(q00.b);
            const float2 f01a = __half22float2(q01.a), f01b = __half22float2(q01.b);
            const float2 f10a = __half22float2(q10.a), f10b = __half22float2(q10.b);
            const float2 f11a = __half22float2(q11.a), f11b = __half22float2(q11.b);

            acc0 = w00 * (wx0 * f00a.x + wx1 * f00b.x)
                 + w01 * (wx0 * f01a.x + wx1 * f01b.x)
                 + w10 * (wx0 * f10a.x + wx1 * f10b.x)
                 + w11 * (wx0 * f11a.x + wx1 * f11b.x);
            acc1 = w00 * (wx0 * f00a.y + wx1 * f00b.y)
                 + w01 * (wx0 * f01a.y + wx1 * f01b.y)
                 + w10 * (wx0 * f10a.y + wx1 * f10b.y)
                 + w11 * (wx0 * f11a.y + wx1 * f11b.y);
        } else {
            // rare exact fallback: planar fp32 global reads, clamped, weight-zeroed
            const int zc0 = min(max(z0, 0), D - 1), zc1 = min(max(z0 + 1, 0), D - 1);
            const int yc0 = min(max(y0, 0), H - 1), yc1 = min(max(y0 + 1, 0), H - 1);
            const int xc0 = min(max(x0, 0), W - 1), xc1 = min(max(x0 + 1, 0), W - 1);
            const int g00 = (zc0 * H + yc0) * W, g01 = (zc0 * H + yc1) * W;
            const int g10 = (zc1 * H + yc0) * W, g11 = (zc1 * H + yc1) * W;
            acc0 = w00 * (wx0 * src[g00 + xc0] + wx1 * src[g00 + xc1])
                 + w01 * (wx0 * src[g01 + xc0] + wx1 * src[g01 + xc1])
                 + w10 * (wx0 * src[g10 + xc0] + wx1 * src[g10 + xc1])
                 + w11 * (wx0 * src[g11 + xc0] + wx1 * src[g11 + xc1]);
            acc1 = w00 * (wx0 * src[N + g00 + xc0] + wx1 * src[N + g00 + xc1])
                 + w01 * (wx0 * src[N + g01 + xc0] + wx1 * src[N + g01 + xc1])
                 + w10 * (wx0 * src[N + g10 + xc0] + wx1 * src[N + g10 + xc1])
                 + w11 * (wx0 * src[N + g11 + xc0] + wx1 * src[N + g11 + xc1]);
        }

        out[vidx[i]]     = acc0;
        out[N + vidx[i]] = acc1;
    }
}

extern "C" void kernel_launch(void* const* d_in, const int* in_sizes, int n_in,
                              void* d_out, int out_size, void* d_ws, size_t ws_size,
                              hipStream_t stream) {
    const float* src  = (const float*)d_in[0];
    const float* flow = (const float*)d_in[1];
    float* out = (float*)d_out;

    dim3 grid(W / BX, H / BY, D / BZ);   // 4 x 24 x 20 = 1920 blocks
    warp3d_h2_kernel<<<grid, NTHR, 0, stream>>>(src, flow, out);
}

// Round 6
// 64.243 us; speedup vs baseline: 2.3507x; 1.2439x over previous
//
#include <hip/hip_runtime.h>
#include <hip/hip_fp16.h>

// src:  [1,2,160,192,224] f32, flow: [1,3,160,192,224] f32, out: [1,2,160,192,224] f32
constexpr int D = 160;
constexpr int H = 192;
constexpr int W = 224;
constexpr int N = D * H * W;

// Tile: 8(z) x 8(y) x 56(x) outputs; halo 4 -> staged 16 x 16 x 64 half2 = 64 KB.
// 1024 threads (16 waves). Persistent blocks (1/CU) walk tiles stride-256 and
// software-pipeline: issue stage loads for tile t+1 into REGISTERS, gather tile t
// from LDS (hides HBM latency), then sync + ds_write + sync.
constexpr int BZ = 8, BY = 8, BX = 56;
constexpr int HA = 4;
constexpr int SZ = 16, SY = 16, SX = 64;
constexpr int NTHR = 1024;
constexpr int NBLK = 256;
constexpr int NTX = W / BX;           // 4
constexpr int NTY = H / BY;           // 24
constexpr int NTZ = D / BZ;           // 20
constexpr int NTILES = NTX * NTY * NTZ; // 1920
constexpr int NVOX = BZ * BY * BX;    // 3584

struct h2p { __half2 a, b; };
__device__ __forceinline__ h2p ld_pair(const __half2* p) {
    h2p v; __builtin_memcpy(&v, p, sizeof(v)); return v;
}

__global__ __launch_bounds__(NTHR, 4) void warp3d_pipe_kernel(
    const float* __restrict__ src,
    const float* __restrict__ flow,
    float* __restrict__ out)
{
    __shared__ __half2 tile[SZ * SY * SX];   // 64 KB

    const int tid  = threadIdx.x;
    const int u    = tid & 63;    // staged x lane
    const int wrow = tid >> 6;    // staged y row (0..15), fixed per thread
    const bool has4 = (tid < NVOX - 3 * NTHR);  // first 512 threads own a 4th voxel

    float sA[SZ], sB[SZ];                   // staged ch0/ch1, one per z-slab
    float fzn[4], fyn[4], fxn[4];           // raw flow, next tile
    float fzc[4], fyc[4], fxc[4];           // raw flow, current tile

    // ---- issue all global loads for tile t (stage rows + flow), no waits ----
    auto issue = [&](int t) {
        const int bx = t & 3; const int q = t >> 2;
        const int by = q % NTY; const int bz = q / NTY;
        const int tz0 = bz * BZ - HA, ty0 = by * BY - HA, tx0 = bx * BX - HA;
        const int gx = min(max(tx0 + u, 0), W - 1);
        const int gy = min(max(ty0 + wrow, 0), H - 1);
        const int rowb = gy * W + gx;
        #pragma unroll
        for (int k = 0; k < SZ; ++k) {
            const int gz = min(max(tz0 + k, 0), D - 1);
            const int ga = gz * (H * W) + rowb;
            sA[k] = src[ga];
            sB[k] = src[N + ga];
        }
        #pragma unroll
        for (int i = 0; i < 4; ++i) {
            if (i < 3 || has4) {
                const int v  = tid + i * NTHR;
                const int lx = v % BX;
                const int qq = v / BX;
                const int ly = qq % BY;
                const int lz = qq / BY;
                const int vi = ((bz * BZ + lz) * H + by * BY + ly) * W + bx * BX + lx;
                fzn[i] = flow[vi];
                fyn[i] = flow[N + vi];
                fxn[i] = flow[2 * N + vi];
            }
        }
    };

    // ---- convert + write staged rows to LDS (compiler inserts the vmcnt wait) ----
    auto commit = [&]() {
        #pragma unroll
        for (int k = 0; k < SZ; ++k) {
            tile[(((k << 4) + wrow) << 6) + u] = __floats2half2_rn(sA[k], sB[k]);
        }
    };

    auto shift_flow = [&]() {
        #pragma unroll
        for (int i = 0; i < 4; ++i) { fzc[i] = fzn[i]; fyc[i] = fyn[i]; fxc[i] = fxn[i]; }
    };

    // ---- gather tile t from LDS using fzc/fyc/fxc ----
    auto gather = [&](int t) {
        const int bx = t & 3; const int q = t >> 2;
        const int by = q % NTY; const int bz = q / NTY;
        const int tz0 = bz * BZ - HA, ty0 = by * BY - HA, tx0 = bx * BX - HA;
        #pragma unroll
        for (int i = 0; i < 4; ++i) {
            if (i == 3 && !has4) break;   // wave-uniform
            const int v  = tid + i * NTHR;
            const int lx = v % BX;
            const int qq = v / BX;
            const int ly = qq % BY;
            const int lz = qq / BY;
            const int gx = bx * BX + lx, gy = by * BY + ly, gz = bz * BZ + lz;
            const int vi = (gz * H + gy) * W + gx;

            const float pz = fzc[i] + (float)gz;
            const float py = fyc[i] + (float)gy;
            const float px = fxc[i] + (float)gx;

            const float z0f = floorf(pz), y0f = floorf(py), x0f = floorf(px);
            const float fz = pz - z0f, fy = py - y0f, fx = px - x0f;
            const int z0 = (int)z0f, y0 = (int)y0f, x0 = (int)x0f;

            const float wz0 = ((unsigned)z0       < (unsigned)D) ? (1.0f - fz) : 0.0f;
            const float wz1 = ((unsigned)(z0 + 1) < (unsigned)D) ? fz          : 0.0f;
            const float wy0 = ((unsigned)y0       < (unsigned)H) ? (1.0f - fy) : 0.0f;
            const float wy1 = ((unsigned)(y0 + 1) < (unsigned)H) ? fy          : 0.0f;
            const float wx0 = ((unsigned)x0       < (unsigned)W) ? (1.0f - fx) : 0.0f;
            const float wx1 = ((unsigned)(x0 + 1) < (unsigned)W) ? fx          : 0.0f;

            const float w00 = wz0 * wy0, w01 = wz0 * wy1;
            const float w10 = wz1 * wy0, w11 = wz1 * wy1;

            const int a0 = z0 - tz0;
            const int b0 = y0 - ty0;
            const int u0 = x0 - tx0;
            const bool intile = ((unsigned)a0 < (unsigned)(SZ - 1)) &&
                                ((unsigned)b0 < (unsigned)(SY - 1)) &&
                                ((unsigned)u0 < (unsigned)(SX - 1));

            float acc0, acc1;
            if (intile) {
                const int r00 = (((a0 << 4) + b0) << 6) + u0;
                const h2p q00 = ld_pair(&tile[r00]);
                const h2p q01 = ld_pair(&tile[r00 + SX]);
                const h2p q10 = ld_pair(&tile[r00 + SY * SX]);
                const h2p q11 = ld_pair(&tile[r00 + SY * SX + SX]);

                const float2 f00a = __half22float2(q00.a), f00b = __half22float2(q00.b);
                const float2 f01a = __half22float2(q01.a), f01b = __half22float2(q01.b);
                const float2 f10a = __half22float2(q10.a), f10b = __half22float2(q10.b);
                const float2 f11a = __half22float2(q11.a), f11b = __half22float2(q11.b);

                acc0 = w00 * (wx0 * f00a.x + wx1 * f00b.x)
                     + w01 * (wx0 * f01a.x + wx1 * f01b.x)
                     + w10 * (wx0 * f10a.x + wx1 * f10b.x)
                     + w11 * (wx0 * f11a.x + wx1 * f11b.x);
                acc1 = w00 * (wx0 * f00a.y + wx1 * f00b.y)
                     + w01 * (wx0 * f01a.y + wx1 * f01b.y)
                     + w10 * (wx0 * f10a.y + wx1 * f10b.y)
                     + w11 * (wx0 * f11a.y + wx1 * f11b.y);
            } else {
                // |flow| >= 4 near a tile face (P ~ 1e-5): exact fp32 global fallback
                const int zc0 = min(max(z0, 0), D - 1), zc1 = min(max(z0 + 1, 0), D - 1);
                const int yc0 = min(max(y0, 0), H - 1), yc1 = min(max(y0 + 1, 0), H - 1);
                const int xc0 = min(max(x0, 0), W - 1), xc1 = min(max(x0 + 1, 0), W - 1);
                const int g00 = (zc0 * H + yc0) * W, g01 = (zc0 * H + yc1) * W;
                const int g10 = (zc1 * H + yc0) * W, g11 = (zc1 * H + yc1) * W;
                acc0 = w00 * (wx0 * src[g00 + xc0] + wx1 * src[g00 + xc1])
                     + w01 * (wx0 * src[g01 + xc0] + wx1 * src[g01 + xc1])
                     + w10 * (wx0 * src[g10 + xc0] + wx1 * src[g10 + xc1])
                     + w11 * (wx0 * src[g11 + xc0] + wx1 * src[g11 + xc1]);
                acc1 = w00 * (wx0 * src[N + g00 + xc0] + wx1 * src[N + g00 + xc1])
                     + w01 * (wx0 * src[N + g01 + xc0] + wx1 * src[N + g01 + xc1])
                     + w10 * (wx0 * src[N + g10 + xc0] + wx1 * src[N + g10 + xc1])
                     + w11 * (wx0 * src[N + g11 + xc0] + wx1 * src[N + g11 + xc1]);
            }

            out[vi]     = acc0;
            out[N + vi] = acc1;
        }
    };

    // ---- persistent pipeline over tiles blockIdx.x + k*NBLK ----
    int tcur = blockIdx.x;
    issue(tcur);
    commit();
    shift_flow();
    __syncthreads();

    int tnext = tcur + NBLK;
    while (true) {
        const bool more = (tnext < NTILES);
        if (more) issue(tnext);       // loads in flight during gather below
        gather(tcur);
        if (!more) break;
        __syncthreads();              // everyone done reading tile tcur
        commit();                     // waits loads, writes tile tnext
        shift_flow();
        __syncthreads();              // tile tnext visible to all
        tcur = tnext;
        tnext += NBLK;
    }
}

extern "C" void kernel_launch(void* const* d_in, const int* in_sizes, int n_in,
                              void* d_out, int out_size, void* d_ws, size_t ws_size,
                              hipStream_t stream) {
    const float* src  = (const float*)d_in[0];
    const float* flow = (const float*)d_in[1];
    float* out = (float*)d_out;

    warp3d_pipe_kernel<<<NBLK, NTHR, 0, stream>>>(src, flow, out);
}